// Round 1
// baseline (223.430 us; speedup 1.0000x reference)
//
#include <hip/hip_runtime.h>
#include <hip/hip_bf16.h>

// Problem dims (fixed by the reference):
#define BB 1024
#define AA 25
#define NN 250   // graph_size
#define PP 250   // patrol nodes

// One block per (b,a) pair.
//  - node_last_visit[ba] -> nv; idx = patrol_index[nv]
//  - zuobiao = nodes_coords[nv] (2 scalars, block-uniform)
//  - stage state row (750 f32) + adj row (250 f32) in LDS
//  - write 1500 f32 = 375 float4, fully coalesced & 16B aligned
__global__ __launch_bounds__(256) void policy_kernel(
    const float* __restrict__ state,         // [B*A, N*3]
    const float* __restrict__ nodes_coords,  // [P, 2]
    const float* __restrict__ adj,           // [P, N]
    const int*   __restrict__ nlv,           // [B*A]
    const int*   __restrict__ patrol_index,  // [P]
    float* __restrict__ out)                 // [B*A, N*6]
{
    __shared__ float s_state[NN * 3];  // 3000 B
    __shared__ float s_adj[NN];        // 1000 B

    const int ba  = blockIdx.x;
    const int tid = threadIdx.x;

    // Block-uniform scalars (same-address loads broadcast).
    const int nv  = nlv[ba];
    const int idx = patrol_index[nv];
    const float zx = nodes_coords[2 * nv + 0];
    const float zy = nodes_coords[2 * nv + 1];

    const float* st = state + (size_t)ba * (NN * 3);  // base 3000B*ba -> 8B aligned
    const float* ad = adj   + (size_t)idx * NN;

    // Stage state row: 375 float2 coalesced loads.
    {
        const float2* st2 = (const float2*)st;
        float2* ss2 = (float2*)s_state;
        for (int i = tid; i < (NN * 3) / 2; i += 256)
            ss2[i] = st2[i];
    }
    // Stage adj row: 250 dword loads (L2-resident, adj is only 250 KB total).
    if (tid < NN) s_adj[tid] = ad[tid];
    __syncthreads();

    float* op = out + (size_t)ba * (NN * 6);  // base 6000B*ba -> 16B aligned
    float4* op4 = (float4*)op;

    // 12-float group g covers nodes n0=2g, n0+1:
    //   q=3g+0 : (s[3n0+0], s[3n0+1], s[3n0+2], zx)
    //   q=3g+1 : (zy, adj[n0], s[3n0+3], s[3n0+4])
    //   q=3g+2 : (s[3n0+5], zx, zy, adj[n0+1])
    for (int q = tid; q < (NN * 6) / 4; q += 256) {
        const int g  = q / 3;
        const int r  = q - 3 * g;
        const int n0 = 2 * g;
        const int sb = 3 * n0;
        float4 v;
        if (r == 0) {
            v.x = s_state[sb + 0];
            v.y = s_state[sb + 1];
            v.z = s_state[sb + 2];
            v.w = zx;
        } else if (r == 1) {
            v.x = zy;
            v.y = s_adj[n0];
            v.z = s_state[sb + 3];
            v.w = s_state[sb + 4];
        } else {
            v.x = s_state[sb + 5];
            v.y = zx;
            v.z = zy;
            v.w = s_adj[n0 + 1];
        }
        op4[q] = v;
    }
}

extern "C" void kernel_launch(void* const* d_in, const int* in_sizes, int n_in,
                              void* d_out, int out_size, void* d_ws, size_t ws_size,
                              hipStream_t stream) {
    const float* state        = (const float*)d_in[0];
    const float* nodes_coords = (const float*)d_in[1];
    const float* adj          = (const float*)d_in[2];
    const int*   nlv          = (const int*)d_in[3];
    const int*   patrol_index = (const int*)d_in[4];
    float* out = (float*)d_out;

    policy_kernel<<<dim3(BB * AA), dim3(256), 0, stream>>>(
        state, nodes_coords, adj, nlv, patrol_index, out);
}